// Round 10
// baseline (233.520 us; speedup 1.0000x reference)
//
#include <hip/hip_runtime.h>
#include <stdint.h>

#define NB 8
#define NP 100
#define NT 500
#define NV 128
#define NBP 800        // NB*NP
#define TS 512         // tok2 per-path stream stride (u8)
#define NITEMS (NB * NT * 50)  // 200000 items; item = (row R, path-pair pp)
#define ROWD 129       // k_dp LDS token row stride in dwords (128 + 1 pad)

typedef unsigned long long u64;

// rotl via single v_alignbit_b32: alignbit(x,x,32-r) = rotr(x,32-r) = rotl(x,r)
#define ROTL(x, r) __builtin_amdgcn_alignbit((x), (x), 32 - (r))

// ---------------- Threefry-2x32, key = (0,1) (jax.random.key(1)) ----------------
__device__ __forceinline__ uint32_t threefry01_lo(uint32_t x0, uint32_t x1) {
  const uint32_t k0 = 0u, k1 = 1u;
  const uint32_t k2 = 0x1BD11BDAu ^ k0 ^ k1;  // 0x1BD11BDB
  x0 += k0; x1 += k1;
#define TF_R(r) { x0 += x1; x1 = ROTL(x1, r); x1 ^= x0; }
  TF_R(13) TF_R(15) TF_R(26) TF_R(6)
  x0 += k1; x1 += k2 + 1u;
  TF_R(17) TF_R(29) TF_R(16) TF_R(24)
  x0 += k2; x1 += k0 + 2u;
  TF_R(13) TF_R(15) TF_R(26) TF_R(6)
  x0 += k0; x1 += k1 + 3u;
  TF_R(17) TF_R(29) TF_R(16) TF_R(24)
  x0 += k1; x1 += k2 + 4u;
  TF_R(13) TF_R(15) TF_R(26) TF_R(6)
  x1 += k0 + 5u;            // x0's final add is dead — only the low word is used
#undef TF_R
  return x1;
}

// ---------------- Kernel 1: Gumbel sampling, argmin over V=128 -----------------
// argmax_v(0.5*e + g_v) == argmin_v((-log2 u_v) * exp(-0.5*e_v)).
// Lane QUAD splits the 128-v range (32 each), combined by 2x shfl_xor with
// exact first-index tiebreak. Each thread handles 2 paths (ILP-2).
// Two half-grid dispatches (item_base param) so k_dp can surface in top-5.
__global__ __launch_bounds__(256) void k_sample(
    const float* __restrict__ em, const int* __restrict__ elen,
    uint8_t* __restrict__ tok2, float* __restrict__ lp2t, int item_base) {
  __shared__ float snw[3][NV + 1];  // -exp2(e * -0.5*log2e); block spans <=3 rows
  const int tid = threadIdx.x;
  const int i0 = item_base + blockIdx.x * 64;   // first item of this block
  const int R0 = i0 / 50;
  for (int i = tid; i < 3 * NV; i += 256) {     // stage 3 rows
    const int r = i >> 7, v = i & 127;
    int R = R0 + r; R = R < NB * NT ? R : NB * NT - 1;
    snw[r][v] = -__builtin_amdgcn_exp2f(em[(size_t)R * NV + v] * -0.7213475204444817f);
  }
  __syncthreads();
  const int item = i0 + (tid >> 2);
  const int q = tid & 3;
  if (item >= NITEMS) return;
  const int R = item / 50;
  const int pp = item - R * 50;
  const int b = R / NT;
  const int t = R - b * NT;
  if (t >= elen[b]) return;  // frames beyond length never consumed (quads exit together)
  const int r = R - R0;
  const int vh = q << 5;
  const int bp0 = b * NP + 2 * pp;
  const uint32_t base0 = ((uint32_t)(bp0 * NT + t) << 7) + (uint32_t)vh;
  const uint32_t base1 = base0 + (uint32_t)(NT << 7);   // path +1
  const float span = (float)(1.0 - 1e-6) - 1e-6f;
  float best0 = 3.0e38f, best1 = 3.0e38f;
  int bi0 = 0, bi1 = 0;
#pragma unroll 8
  for (int i = 0; i < 32; i++) {
    // partitionable threefry: bits[idx] = low output of threefry(key, idx>>32, idx)
    const uint32_t r0 = threefry01_lo(0u, base0 + (uint32_t)i);
    const uint32_t r1 = threefry01_lo(0u, base1 + (uint32_t)i);
    const float f0 = __uint_as_float((r0 >> 9) | 0x3f800000u) - 1.0f;
    const float f1 = __uint_as_float((r1 >> 9) | 0x3f800000u) - 1.0f;
    const float u0 = fmaf(f0, span, 1e-6f);   // clamp dropped: fma >= 1e-6 always
    const float u1 = fmaf(f1, span, 1e-6f);
    const float w = snw[r][vh + i];
    const float s0 = __log2f(u0) * w;         // (-log2 u) * exp(-e/2) > 0
    const float s1 = __log2f(u1) * w;
    if (s0 < best0) { best0 = s0; bi0 = vh + i; }  // strict < = first-index tiebreak
    if (s1 < best1) { best1 = s1; bi1 = vh + i; }
  }
  // quad butterfly combine: lower score wins, tie -> lower v
#pragma unroll
  for (int off = 1; off <= 2; off <<= 1) {
    const float oa = __shfl_xor(best0, off); const int ia = __shfl_xor(bi0, off);
    if (oa < best0 || (oa == best0 && ia < bi0)) { best0 = oa; bi0 = ia; }
    const float ob = __shfl_xor(best1, off); const int ib = __shfl_xor(bi1, off);
    if (ob < best1 || (ob == best1 && ib < bi1)) { best1 = ob; bi1 = ib; }
  }
  if (q == 0) {
    const float e0 = em[(size_t)R * NV + bi0];
    const float e1 = em[(size_t)R * NV + bi1];
    tok2[(size_t)bp0 * TS + t] = (uint8_t)bi0;
    tok2[(size_t)(bp0 + 1) * TS + t] = (uint8_t)bi1;
    *(float2*)&lp2t[(size_t)t * NBP + bp0] = make_float2(e0, e1);  // coalesced
  }
}

// ---------------- Kernel 2: CTC collapse + Myers bit-parallel edit distance ----
// grid (8,2) x 64: block (b,h) = 50 paths, lane = path. Tokens bulk-staged to
// LDS (row stride 129 dwords -> 2-way banks, free); Myers loop has ZERO global
// loads. hw=1 hardcoded (m in [80,100] => high word). Branchless kept-gating.
struct Eq4 { u64 e0[4], e1[4]; int cc[4]; };

__device__ __forceinline__ void ext4(uint32_t wbits, const uint32_t* __restrict__ pqf,
                                     Eq4& E) {
#pragma unroll
  for (int i = 0; i < 4; i++) {
    const int byte = (wbits >> (8 * i)) & 255;
    const int c = byte & 127;
    E.cc[i] = byte;
    E.e0[i] = (u64)pqf[c] | ((u64)pqf[128 + c] << 32);
    E.e1[i] = (u64)pqf[256 + c] | ((u64)pqf[384 + c] << 32);
  }
}

__device__ __forceinline__ void proc4(const Eq4& E, int fbase, int myel, u64 hmask,
                                      u64& Pv0, u64& Pv1, u64& Mv0, u64& Mv1,
                                      int& score, int& prev) {
#pragma unroll
  for (int i = 0; i < 4; i++) {
    if (fbase + i >= myel) break;  // uniform per block
    const int c = E.cc[i];
    const bool kept = (c != 0) & (c != prev);
    prev = c;
    const u64 Eq0 = E.e0[i], Eq1 = E.e1[i];
    const u64 Xv0 = Eq0 | Mv0, Xv1 = Eq1 | Mv1;
    const u64 EP0 = Eq0 & Pv0, EP1 = Eq1 & Pv1;
    const u64 sA = EP0 + Pv0;
    const u64 sB = EP1 + Pv1 + (sA < EP0 ? 1ull : 0ull);
    const u64 Xh0 = (sA ^ Pv0) | Eq0;
    const u64 Xh1 = (sB ^ Pv1) | Eq1;
    const u64 Ph0 = Mv0 | ~(Xh0 | Pv0);
    const u64 Ph1 = Mv1 | ~(Xh1 | Pv1);
    const u64 Mh0 = Pv0 & Xh0, Mh1 = Pv1 & Xh1;
    const int d = (int)((Ph1 & hmask) != 0) - (int)((Mh1 & hmask) != 0);
    const u64 nPh1 = (Ph1 << 1) | (Ph0 >> 63);
    const u64 nPh0 = (Ph0 << 1) | 1ull;  // dp[i][0] = i boundary
    const u64 nMh1 = (Mh1 << 1) | (Mh0 >> 63);
    const u64 nMh0 = (Mh0 << 1);
    // branchless gate (cndmask): dropped frames leave state unchanged
    score += kept ? d : 0;
    Pv0 = kept ? (nMh0 | ~(Xv0 | nPh0)) : Pv0;
    Pv1 = kept ? (nMh1 | ~(Xv1 | nPh1)) : Pv1;
    Mv0 = kept ? (nPh0 & Xv0) : Mv0;
    Mv1 = kept ? (nPh1 & Xv1) : Mv1;
  }
}

__global__ __launch_bounds__(64) void k_dp(
    const uint8_t* __restrict__ tok2,
    const int* __restrict__ elen, const int* __restrict__ labels,
    const int* __restrict__ llen, float* __restrict__ wer) {
  __shared__ uint32_t pq[4][NV];        // 2 KB, bank = c%32
  __shared__ uint32_t tokL[50 * ROWD];  // 25.8 KB token slab (50 paths)
  const int b = blockIdx.x, h = blockIdx.y;
  const int tid = threadIdx.x;
  // ---- bulk token staging: 6400 dwords, coalesced, unroll-8 MLP ----
  const uint32_t* __restrict__ src =
      (const uint32_t*)(tok2 + (size_t)(b * NP + h * 50) * TS);
#pragma unroll 8
  for (int i = 0; i < 100; i++) {
    const int gi = i * 64 + tid;        // dword index in the slab
    const int row = gi >> 7, col = gi & 127;
    tokL[row * ROWD + col] = src[gi];
  }
  // ---- peq build: thread = 2 token columns ----
  const int m = llen[b];  // ref_len in [80,100], uniform => high word holds bit m-1
  {
    const int* __restrict__ lab = labels + b * 100;  // L == 100
    const int e0 = m < 32 ? m : 32, e1 = m < 64 ? m : 64;
    const int e2 = m < 96 ? m : 96, e3 = m;
#pragma unroll
    for (int hh = 0; hh < 2; hh++) {
      const int c = tid + hh * 64;
      uint32_t a0 = 0, a1 = 0, a2 = 0, a3 = 0;
      for (int i = 0; i < e0; i++)  a0 |= (uint32_t)(lab[i] == c) << i;
      for (int i = 32; i < e1; i++) a1 |= (uint32_t)(lab[i] == c) << (i - 32);
      for (int i = 64; i < e2; i++) a2 |= (uint32_t)(lab[i] == c) << (i - 64);
      for (int i = 96; i < e3; i++) a3 |= (uint32_t)(lab[i] == c) << (i - 96);
      pq[0][c] = a0; pq[1][c] = a1; pq[2][c] = a2; pq[3][c] = a3;
    }
  }
  __syncthreads();
  const uint32_t* __restrict__ pqf = &pq[0][0];
  const bool active = (tid < 50);
  const int pl = active ? tid : 49;
  const uint32_t* __restrict__ tp = tokL + pl * ROWD;
  const int myel = elen[b];  // uniform
  u64 Pv0 = ~0ull, Pv1 = ~0ull, Mv0 = 0ull, Mv1 = 0ull;
  int score = m, prev = -1;
  const u64 hmask = 1ull << ((m - 1) & 63);  // hw==1 always (m >= 80)

  const int ng = (myel + 3) >> 2;       // 4-frame groups, <= 125
  Eq4 A, B;
  ext4(tp[0], pqf, A);
  int g = 0;
  for (; g + 1 < ng; g += 2) {
    ext4(tp[g + 1], pqf, B);            // extract next while processing current
    proc4(A, g * 4, myel, hmask, Pv0, Pv1, Mv0, Mv1, score, prev);
    if (g + 2 < ng) ext4(tp[g + 2], pqf, A);
    proc4(B, (g + 1) * 4, myel, hmask, Pv0, Pv1, Mv0, Mv1, score, prev);
  }
  if (g < ng) proc4(A, g * 4, myel, hmask, Pv0, Pv1, Mv0, Mv1, score, prev);
  if (active) wer[b * NP + h * 50 + tid] = (float)score;
}

// ---------------- Kernel 3: per-path logp sum over t ([t][bp] layout) ----------
// block per b, thread = path: each step the block reads 100 consecutive f32.
__global__ __launch_bounds__(128) void k_red(
    const float* __restrict__ lp2t, const int* __restrict__ elen,
    float* __restrict__ slp) {
  const int b = blockIdx.x;
  const int tid = threadIdx.x;
  const bool active = (tid < NP);
  const int p = active ? tid : NP - 1;
  const int el = elen[b];  // uniform
  const float* __restrict__ col = lp2t + b * NP + p;
  double s = 0.0;
#pragma unroll 8
  for (int t = 0; t < el; t++) s += (double)col[(size_t)t * NBP];
  if (active) slp[b * NP + p] = (float)s;
}

// ---------------- Kernel 4: per-b softmax + expected WER + mean ----------------
__global__ __launch_bounds__(512) void k_fin(
    const float* __restrict__ slp, const float* __restrict__ wer,
    float* __restrict__ out) {
  __shared__ float partial[NB];
  const int w = threadIdx.x >> 6, lane = threadIdx.x & 63;  // w = b
  const int base = w * NP;
  const float l0 = (lane < NP) ? slp[base + lane] : -1e30f;
  const float l1 = (lane + 64 < NP) ? slp[base + lane + 64] : -1e30f;
  float mx = fmaxf(l0, l1);
  for (int off = 1; off < 64; off <<= 1) mx = fmaxf(mx, __shfl_xor(mx, off));
  const float e0 = (lane < NP) ? __expf(l0 - mx) : 0.0f;
  const float e1 = (lane + 64 < NP) ? __expf(l1 - mx) : 0.0f;
  const float w0 = (lane < NP) ? wer[base + lane] : 0.0f;
  const float w1 = (lane + 64 < NP) ? wer[base + lane + 64] : 0.0f;
  float s = e0 + e1;
  float a = e0 * w0 + e1 * w1;
  for (int off = 1; off < 64; off <<= 1) {
    s += __shfl_xor(s, off);
    a += __shfl_xor(a, off);
  }
  if (lane == 0) partial[w] = a / s;
  __syncthreads();
  if (threadIdx.x == 0) {
    float tot = 0.0f;
    for (int i = 0; i < NB; i++) tot += partial[i];
    out[0] = tot * (1.0f / (float)NBP);
  }
}

extern "C" void kernel_launch(void* const* d_in, const int* in_sizes, int n_in,
                              void* d_out, int out_size, void* d_ws, size_t ws_size,
                              hipStream_t stream) {
  const float* em     = (const float*)d_in[0];
  const int*   elen   = (const int*)d_in[1];
  const int*   labels = (const int*)d_in[2];
  const int*   llen   = (const int*)d_in[3];
  float* out = (float*)d_out;
  char* ws = (char*)d_ws;
  uint8_t* tok2 = (uint8_t*)ws;                                    // 409.6 KB
  float* lp2t   = (float*)(ws + (size_t)NBP * TS);                 // 1.6 MB ([t][bp])
  float* wer    = (float*)(ws + (size_t)NBP * TS + (size_t)NT * NBP * 4);
  float* slp    = (float*)(ws + (size_t)NBP * TS + (size_t)NT * NBP * 4 + NBP * 4);

  // 3125 blocks total, split in two dispatches (1563 + 1562) for profiling vis.
  k_sample<<<dim3(1563), dim3(256), 0, stream>>>(em, elen, tok2, lp2t, 0);
  k_sample<<<dim3(1562), dim3(256), 0, stream>>>(em, elen, tok2, lp2t, 1563 * 64);
  k_dp<<<dim3(NB, 2), dim3(64), 0, stream>>>(tok2, elen, labels, llen, wer);
  k_red<<<dim3(NB), dim3(128), 0, stream>>>(lp2t, elen, slp);
  k_fin<<<dim3(1), dim3(512), 0, stream>>>(slp, wer, out);
}

// Round 11
// 208.198 us; speedup vs baseline: 1.1216x; 1.1216x over previous
//
#include <hip/hip_runtime.h>
#include <stdint.h>

#define NB 8
#define NP 100
#define NT 500
#define NV 128
#define NBP 800        // NB*NP
#define TS 512         // tok2 per-path stream stride (u8)
#define NITEMS (NB * NT * 50)  // 200000 items; item = (row R, path-pair pp)

typedef unsigned long long u64;

// rotl via single v_alignbit_b32: alignbit(x,x,32-r) = rotr(x,32-r) = rotl(x,r)
#define ROTL(x, r) __builtin_amdgcn_alignbit((x), (x), 32 - (r))

// ---------------- Threefry-2x32, key = (0,1) (jax.random.key(1)) ----------------
__device__ __forceinline__ uint32_t threefry01_lo(uint32_t x0, uint32_t x1) {
  const uint32_t k0 = 0u, k1 = 1u;
  const uint32_t k2 = 0x1BD11BDAu ^ k0 ^ k1;  // 0x1BD11BDB
  x0 += k0; x1 += k1;
#define TF_R(r) { x0 += x1; x1 = ROTL(x1, r); x1 ^= x0; }
  TF_R(13) TF_R(15) TF_R(26) TF_R(6)
  x0 += k1; x1 += k2 + 1u;
  TF_R(17) TF_R(29) TF_R(16) TF_R(24)
  x0 += k2; x1 += k0 + 2u;
  TF_R(13) TF_R(15) TF_R(26) TF_R(6)
  x0 += k0; x1 += k1 + 3u;
  TF_R(17) TF_R(29) TF_R(16) TF_R(24)
  x0 += k1; x1 += k2 + 4u;
  TF_R(13) TF_R(15) TF_R(26) TF_R(6)
  x1 += k0 + 5u;            // x0's final add is dead — only the low word is used
#undef TF_R
  return x1;
}

// ---------------- Kernel 1: Gumbel sampling, argmin over V=128 -----------------
// argmax_v(0.5*e + g_v) == argmin_v((-log2 u_v) * exp(-0.5*e_v)).
// Lane QUAD splits the 128-v range (32 each), combined by 2x shfl_xor with
// exact first-index tiebreak. Each thread handles 2 paths (ILP-2).
__global__ __launch_bounds__(256) void k_sample(
    const float* __restrict__ em, const int* __restrict__ elen,
    uint8_t* __restrict__ tok2, float* __restrict__ lp2t, int item_base) {
  __shared__ float snw[3][NV + 1];  // -exp2(e * -0.5*log2e); block spans <=3 rows
  const int tid = threadIdx.x;
  const int i0 = item_base + blockIdx.x * 64;   // first item of this block
  const int R0 = i0 / 50;
  for (int i = tid; i < 3 * NV; i += 256) {     // stage 3 rows
    const int r = i >> 7, v = i & 127;
    int R = R0 + r; R = R < NB * NT ? R : NB * NT - 1;
    snw[r][v] = -__builtin_amdgcn_exp2f(em[(size_t)R * NV + v] * -0.7213475204444817f);
  }
  __syncthreads();
  const int item = i0 + (tid >> 2);
  const int q = tid & 3;
  if (item >= NITEMS) return;
  const int R = item / 50;
  const int pp = item - R * 50;
  const int b = R / NT;
  const int t = R - b * NT;
  if (t >= elen[b]) return;  // frames beyond length never consumed (quads exit together)
  const int r = R - R0;
  const int vh = q << 5;
  const int bp0 = b * NP + 2 * pp;
  const uint32_t base0 = ((uint32_t)(bp0 * NT + t) << 7) + (uint32_t)vh;
  const uint32_t base1 = base0 + (uint32_t)(NT << 7);   // path +1
  const float span = (float)(1.0 - 1e-6) - 1e-6f;
  float best0 = 3.0e38f, best1 = 3.0e38f;
  int bi0 = 0, bi1 = 0;
#pragma unroll 8
  for (int i = 0; i < 32; i++) {
    // partitionable threefry: bits[idx] = low output of threefry(key, idx>>32, idx)
    const uint32_t r0 = threefry01_lo(0u, base0 + (uint32_t)i);
    const uint32_t r1 = threefry01_lo(0u, base1 + (uint32_t)i);
    const float f0 = __uint_as_float((r0 >> 9) | 0x3f800000u) - 1.0f;
    const float f1 = __uint_as_float((r1 >> 9) | 0x3f800000u) - 1.0f;
    const float u0 = fmaf(f0, span, 1e-6f);   // clamp dropped: fma >= 1e-6 always
    const float u1 = fmaf(f1, span, 1e-6f);
    const float w = snw[r][vh + i];
    const float s0 = __log2f(u0) * w;         // (-log2 u) * exp(-e/2) > 0
    const float s1 = __log2f(u1) * w;
    if (s0 < best0) { best0 = s0; bi0 = vh + i; }  // strict < = first-index tiebreak
    if (s1 < best1) { best1 = s1; bi1 = vh + i; }
  }
  // quad butterfly combine: lower score wins, tie -> lower v
#pragma unroll
  for (int off = 1; off <= 2; off <<= 1) {
    const float oa = __shfl_xor(best0, off); const int ia = __shfl_xor(bi0, off);
    if (oa < best0 || (oa == best0 && ia < bi0)) { best0 = oa; bi0 = ia; }
    const float ob = __shfl_xor(best1, off); const int ib = __shfl_xor(bi1, off);
    if (ob < best1 || (ob == best1 && ib < bi1)) { best1 = ob; bi1 = ib; }
  }
  if (q == 0) {
    const float e0 = em[(size_t)R * NV + bi0];
    const float e1 = em[(size_t)R * NV + bi1];
    tok2[(size_t)bp0 * TS + t] = (uint8_t)bi0;
    tok2[(size_t)(bp0 + 1) * TS + t] = (uint8_t)bi1;
    *(float2*)&lp2t[(size_t)t * NBP + bp0] = make_float2(e0, e1);  // coalesced
  }
}

// ---------------- Kernel 1.5: parallel Eq precompute ---------------------------
// For every (bp, t<el): pack the Myers Eq bitvector (2x u64) for the frame's
// token + the token byte (top byte of word 3; m<=100 => bits 100..127 free)
// into a uint4, stored [t][bp] so k_dp's reads are fully coalesced & linear.
__global__ __launch_bounds__(256) void k_eq(
    const uint8_t* __restrict__ tok2, const int* __restrict__ labels,
    const int* __restrict__ llen, const int* __restrict__ elen,
    uint4* __restrict__ eqt) {
  __shared__ uint32_t pq[4][NV];  // [word-half][token], 2 KB
  const int b = blockIdx.x;       // 8
  const int pg = blockIdx.y;      // 25 path-groups of 4
  const int tid = threadIdx.x;
  const int m = llen[b];          // uniform
  if (tid < NV) {
    const int c = tid;
    const int* __restrict__ lab = labels + b * 100;  // L == 100
    uint32_t a0 = 0, a1 = 0, a2 = 0, a3 = 0;
    const int e0 = m < 32 ? m : 32, e1 = m < 64 ? m : 64;
    const int e2 = m < 96 ? m : 96, e3 = m;
    for (int i = 0; i < e0; i++)  a0 |= (uint32_t)(lab[i] == c) << i;
    for (int i = 32; i < e1; i++) a1 |= (uint32_t)(lab[i] == c) << (i - 32);
    for (int i = 64; i < e2; i++) a2 |= (uint32_t)(lab[i] == c) << (i - 64);
    for (int i = 96; i < e3; i++) a3 |= (uint32_t)(lab[i] == c) << (i - 96);
    pq[0][c] = a0; pq[1][c] = a1; pq[2][c] = a2; pq[3][c] = a3;
  }
  __syncthreads();
  const int el = elen[b];  // uniform
  const int bp0 = b * NP + pg * 4;
  const uint8_t* __restrict__ src = tok2 + (size_t)bp0 * TS;
  for (int f = tid; f < 4 * NT; f += 256) {
    const int pl = f & 3, t = f >> 2;
    if (t >= el) break;   // f ascending => t ascending per thread
    const int c = src[(size_t)pl * TS + t];
    uint4 E;
    E.x = pq[0][c]; E.y = pq[1][c];
    E.z = pq[2][c]; E.w = pq[3][c] | ((uint32_t)c << 24);  // token byte embedded
    eqt[(size_t)t * NBP + bp0 + pl] = E;
  }
}

// ---------------- Kernel 2: CTC collapse + Myers bit-parallel edit distance ----
// grid (8,2) x 64, lane = path. Reads the linear [t][bp] Eq stream with a
// quad-buffered register prefetch (16-28 frame lead). ZERO gathers in the
// serial loop -> pure-ALU Myers chain (~65 cy/frame).
__device__ __forceinline__ void loadg(uint4 (&B)[4], int g, int bp,
                                      const uint4* __restrict__ eqt) {
#pragma unroll
  for (int i = 0; i < 4; i++) {
    int t = g * 4 + i;
    t = t < NT ? t : NT - 1;
    B[i] = eqt[(size_t)t * NBP + bp];
  }
}

__device__ __forceinline__ void procg(const uint4 (&B)[4], int g, int myel,
                                      u64 hmask,
                                      u64& Pv0, u64& Pv1, u64& Mv0, u64& Mv1,
                                      int& score, int& prev) {
#pragma unroll
  for (int i = 0; i < 4; i++) {
    if (g * 4 + i >= myel) break;  // uniform per block
    const int c = B[i].w >> 24;
    const u64 Eq0 = (u64)B[i].x | ((u64)B[i].y << 32);
    const u64 Eq1 = (u64)B[i].z | ((u64)(B[i].w & 0x00FFFFFFu) << 32);
    const bool kept = (c != 0) & (c != prev);
    prev = c;
    const u64 Xv0 = Eq0 | Mv0, Xv1 = Eq1 | Mv1;
    const u64 EP0 = Eq0 & Pv0, EP1 = Eq1 & Pv1;
    const u64 sA = EP0 + Pv0;
    const u64 sB = EP1 + Pv1 + (sA < EP0 ? 1ull : 0ull);
    const u64 Xh0 = (sA ^ Pv0) | Eq0;
    const u64 Xh1 = (sB ^ Pv1) | Eq1;
    const u64 Ph0 = Mv0 | ~(Xh0 | Pv0);
    const u64 Ph1 = Mv1 | ~(Xh1 | Pv1);
    const u64 Mh0 = Pv0 & Xh0, Mh1 = Pv1 & Xh1;
    const int d = (int)((Ph1 & hmask) != 0) - (int)((Mh1 & hmask) != 0);
    const u64 nPh1 = (Ph1 << 1) | (Ph0 >> 63);
    const u64 nPh0 = (Ph0 << 1) | 1ull;  // dp[i][0] = i boundary
    const u64 nMh1 = (Mh1 << 1) | (Mh0 >> 63);
    const u64 nMh0 = (Mh0 << 1);
    // branchless gate: dropped frames leave state unchanged
    score += kept ? d : 0;
    Pv0 = kept ? (nMh0 | ~(Xv0 | nPh0)) : Pv0;
    Pv1 = kept ? (nMh1 | ~(Xv1 | nPh1)) : Pv1;
    Mv0 = kept ? (nPh0 & Xv0) : Mv0;
    Mv1 = kept ? (nPh1 & Xv1) : Mv1;
  }
}

__global__ __launch_bounds__(64) void k_dp(
    const uint4* __restrict__ eqt,
    const int* __restrict__ elen, const int* __restrict__ llen,
    float* __restrict__ wer) {
  const int b = blockIdx.x, h = blockIdx.y;
  const int tid = threadIdx.x;
  const bool active = (tid < 50);
  const int bp = b * NP + h * 50 + (active ? tid : 49);
  const int m = llen[b];     // ref_len in [80,100] => high word holds bit m-1
  const int myel = elen[b];  // uniform
  u64 Pv0 = ~0ull, Pv1 = ~0ull, Mv0 = 0ull, Mv1 = 0ull;
  int score = m, prev = -1;
  const u64 hmask = 1ull << ((m - 1) & 63);

  const int ng = (myel + 3) >> 2;  // 4-frame groups; >= 100 always
  uint4 B0[4], B1[4], B2[4], B3[4];
  loadg(B0, 0, bp, eqt); loadg(B1, 1, bp, eqt);
  loadg(B2, 2, bp, eqt); loadg(B3, 3, bp, eqt);
  int g = 0;
  while (g + 4 <= ng) {
    procg(B0, g,     myel, hmask, Pv0, Pv1, Mv0, Mv1, score, prev);
    loadg(B0, g + 4, bp, eqt);
    procg(B1, g + 1, myel, hmask, Pv0, Pv1, Mv0, Mv1, score, prev);
    loadg(B1, g + 5, bp, eqt);
    procg(B2, g + 2, myel, hmask, Pv0, Pv1, Mv0, Mv1, score, prev);
    loadg(B2, g + 6, bp, eqt);
    procg(B3, g + 3, myel, hmask, Pv0, Pv1, Mv0, Mv1, score, prev);
    loadg(B3, g + 7, bp, eqt);
    g += 4;
  }
  if (g     < ng) procg(B0, g,     myel, hmask, Pv0, Pv1, Mv0, Mv1, score, prev);
  if (g + 1 < ng) procg(B1, g + 1, myel, hmask, Pv0, Pv1, Mv0, Mv1, score, prev);
  if (g + 2 < ng) procg(B2, g + 2, myel, hmask, Pv0, Pv1, Mv0, Mv1, score, prev);
  if (active) wer[bp] = (float)score;
}

// ---------------- Kernel 3: per-path logp partial sums (4 t-chunks) ------------
// f64 partials; k ascending re-summed in k_fin => deterministic, and f64
// absorbs any chunking difference far below f32 resolution.
__global__ __launch_bounds__(128) void k_red(
    const float* __restrict__ lp2t, const int* __restrict__ elen,
    double* __restrict__ pred) {
  const int b = blockIdx.x, k = blockIdx.y;
  const int tid = threadIdx.x;
  const bool active = (tid < NP);
  const int p = active ? tid : NP - 1;
  const int el = elen[b];  // uniform
  const int t0 = k * 125;
  const int t1 = (t0 + 125 < el) ? t0 + 125 : el;
  const float* __restrict__ col = lp2t + b * NP + p;
  double s = 0.0;
#pragma unroll 8
  for (int t = t0; t < t1; t++) s += (double)col[(size_t)t * NBP];
  if (active) pred[(size_t)(b * NP + p) * 4 + k] = s;
}

// ---------------- Kernel 4: per-b softmax + expected WER + mean ----------------
__global__ __launch_bounds__(512) void k_fin(
    const double* __restrict__ pred, const float* __restrict__ wer,
    float* __restrict__ out) {
  __shared__ float partial[NB];
  const int w = threadIdx.x >> 6, lane = threadIdx.x & 63;  // w = b
  const int base = w * NP;
  float l0 = -1e30f, l1 = -1e30f;
  if (lane < NP) {
    const double* pr = pred + (size_t)(base + lane) * 4;
    l0 = (float)(pr[0] + pr[1] + pr[2] + pr[3]);
  }
  if (lane + 64 < NP) {
    const double* pr = pred + (size_t)(base + lane + 64) * 4;
    l1 = (float)(pr[0] + pr[1] + pr[2] + pr[3]);
  }
  float mx = fmaxf(l0, l1);
  for (int off = 1; off < 64; off <<= 1) mx = fmaxf(mx, __shfl_xor(mx, off));
  const float e0 = (lane < NP) ? __expf(l0 - mx) : 0.0f;
  const float e1 = (lane + 64 < NP) ? __expf(l1 - mx) : 0.0f;
  const float w0 = (lane < NP) ? wer[base + lane] : 0.0f;
  const float w1 = (lane + 64 < NP) ? wer[base + lane + 64] : 0.0f;
  float s = e0 + e1;
  float a = e0 * w0 + e1 * w1;
  for (int off = 1; off < 64; off <<= 1) {
    s += __shfl_xor(s, off);
    a += __shfl_xor(a, off);
  }
  if (lane == 0) partial[w] = a / s;
  __syncthreads();
  if (threadIdx.x == 0) {
    float tot = 0.0f;
    for (int i = 0; i < NB; i++) tot += partial[i];
    out[0] = tot * (1.0f / (float)NBP);
  }
}

extern "C" void kernel_launch(void* const* d_in, const int* in_sizes, int n_in,
                              void* d_out, int out_size, void* d_ws, size_t ws_size,
                              hipStream_t stream) {
  const float* em     = (const float*)d_in[0];
  const int*   elen   = (const int*)d_in[1];
  const int*   labels = (const int*)d_in[2];
  const int*   llen   = (const int*)d_in[3];
  float* out = (float*)d_out;
  char* ws = (char*)d_ws;
  uint4*   eqt  = (uint4*)ws;                               // 500*800*16 = 6.4 MB
  uint8_t* tok2 = (uint8_t*)(ws + 6400000);                 // 409.6 KB
  float*   lp2t = (float*)(ws + 6400000 + 409600);          // 1.6 MB ([t][bp])
  float*   wer  = (float*)(ws + 6400000 + 409600 + 1600000);
  double*  pred = (double*)(ws + 6400000 + 409600 + 1600000 + 3200);
  float*   slpX = (float*)(ws + 6400000 + 409600 + 1600000 + 3200 + 25600);
  (void)slpX; (void)ws_size;

  k_sample<<<dim3(1563), dim3(256), 0, stream>>>(em, elen, tok2, lp2t, 0);
  k_sample<<<dim3(1562), dim3(256), 0, stream>>>(em, elen, tok2, lp2t, 1563 * 64);
  k_eq<<<dim3(NB, 25), dim3(256), 0, stream>>>(tok2, labels, llen, elen, eqt);
  k_dp<<<dim3(NB, 2), dim3(64), 0, stream>>>(eqt, elen, llen, wer);
  k_red<<<dim3(NB, 4), dim3(128), 0, stream>>>(lp2t, elen, pred);
  k_fin<<<dim3(1), dim3(512), 0, stream>>>(pred, wer, out);
}

// Round 12
// 199.596 us; speedup vs baseline: 1.1700x; 1.0431x over previous
//
#include <hip/hip_runtime.h>
#include <stdint.h>

#define NB 8
#define NP 100
#define NT 500
#define NV 128
#define NBP 800        // NB*NP
#define TS 512         // tok2 per-path stream stride (u8)
#define ES 500         // eqc per-path stride (uint4 entries)
#define NITEMS (NB * NT * 50)  // 200000 items; item = (row R, path-pair pp)

typedef unsigned long long u64;

// rotl via single v_alignbit_b32: alignbit(x,x,32-r) = rotr(x,32-r) = rotl(x,r)
#define ROTL(x, r) __builtin_amdgcn_alignbit((x), (x), 32 - (r))

// ---------------- Threefry-2x32, key = (0,1) (jax.random.key(1)) ----------------
__device__ __forceinline__ uint32_t threefry01_lo(uint32_t x0, uint32_t x1) {
  const uint32_t k0 = 0u, k1 = 1u;
  const uint32_t k2 = 0x1BD11BDAu ^ k0 ^ k1;  // 0x1BD11BDB
  x0 += k0; x1 += k1;
#define TF_R(r) { x0 += x1; x1 = ROTL(x1, r); x1 ^= x0; }
  TF_R(13) TF_R(15) TF_R(26) TF_R(6)
  x0 += k1; x1 += k2 + 1u;
  TF_R(17) TF_R(29) TF_R(16) TF_R(24)
  x0 += k2; x1 += k0 + 2u;
  TF_R(13) TF_R(15) TF_R(26) TF_R(6)
  x0 += k0; x1 += k1 + 3u;
  TF_R(17) TF_R(29) TF_R(16) TF_R(24)
  x0 += k1; x1 += k2 + 4u;
  TF_R(13) TF_R(15) TF_R(26) TF_R(6)
  x1 += k0 + 5u;            // x0's final add is dead — only the low word is used
#undef TF_R
  return x1;
}

// ---------------- Kernel 1: Gumbel sampling, argmin over V=128 -----------------
// argmax_v(0.5*e + g_v) == argmin_v((-log2 u_v) * exp(-0.5*e_v)).
// Lane QUAD splits the 128-v range (32 each), combined by 2x shfl_xor with
// exact first-index tiebreak. Each thread handles 2 paths (ILP-2).
__global__ __launch_bounds__(256) void k_sample(
    const float* __restrict__ em, const int* __restrict__ elen,
    uint8_t* __restrict__ tok2, float* __restrict__ lp2t, int item_base) {
  __shared__ float snw[3][NV + 1];  // -exp2(e * -0.5*log2e); block spans <=3 rows
  const int tid = threadIdx.x;
  const int i0 = item_base + blockIdx.x * 64;   // first item of this block
  const int R0 = i0 / 50;
  for (int i = tid; i < 3 * NV; i += 256) {     // stage 3 rows
    const int r = i >> 7, v = i & 127;
    int R = R0 + r; R = R < NB * NT ? R : NB * NT - 1;
    snw[r][v] = -__builtin_amdgcn_exp2f(em[(size_t)R * NV + v] * -0.7213475204444817f);
  }
  __syncthreads();
  const int item = i0 + (tid >> 2);
  const int q = tid & 3;
  if (item >= NITEMS) return;
  const int R = item / 50;
  const int pp = item - R * 50;
  const int b = R / NT;
  const int t = R - b * NT;
  if (t >= elen[b]) return;  // frames beyond length never consumed (quads exit together)
  const int r = R - R0;
  const int vh = q << 5;
  const int bp0 = b * NP + 2 * pp;
  const uint32_t base0 = ((uint32_t)(bp0 * NT + t) << 7) + (uint32_t)vh;
  const uint32_t base1 = base0 + (uint32_t)(NT << 7);   // path +1
  const float span = (float)(1.0 - 1e-6) - 1e-6f;
  float best0 = 3.0e38f, best1 = 3.0e38f;
  int bi0 = 0, bi1 = 0;
#pragma unroll 8
  for (int i = 0; i < 32; i++) {
    // partitionable threefry: bits[idx] = low output of threefry(key, idx>>32, idx)
    const uint32_t r0 = threefry01_lo(0u, base0 + (uint32_t)i);
    const uint32_t r1 = threefry01_lo(0u, base1 + (uint32_t)i);
    const float f0 = __uint_as_float((r0 >> 9) | 0x3f800000u) - 1.0f;
    const float f1 = __uint_as_float((r1 >> 9) | 0x3f800000u) - 1.0f;
    const float u0 = fmaf(f0, span, 1e-6f);   // clamp dropped: fma >= 1e-6 always
    const float u1 = fmaf(f1, span, 1e-6f);
    const float w = snw[r][vh + i];
    const float s0 = __log2f(u0) * w;         // (-log2 u) * exp(-e/2) > 0
    const float s1 = __log2f(u1) * w;
    if (s0 < best0) { best0 = s0; bi0 = vh + i; }  // strict < = first-index tiebreak
    if (s1 < best1) { best1 = s1; bi1 = vh + i; }
  }
  // quad butterfly combine: lower score wins, tie -> lower v
#pragma unroll
  for (int off = 1; off <= 2; off <<= 1) {
    const float oa = __shfl_xor(best0, off); const int ia = __shfl_xor(bi0, off);
    if (oa < best0 || (oa == best0 && ia < bi0)) { best0 = oa; bi0 = ia; }
    const float ob = __shfl_xor(best1, off); const int ib = __shfl_xor(bi1, off);
    if (ob < best1 || (ob == best1 && ib < bi1)) { best1 = ob; bi1 = ib; }
  }
  if (q == 0) {
    const float e0 = em[(size_t)R * NV + bi0];
    const float e1 = em[(size_t)R * NV + bi1];
    tok2[(size_t)bp0 * TS + t] = (uint8_t)bi0;
    tok2[(size_t)(bp0 + 1) * TS + t] = (uint8_t)bi1;
    *(float2*)&lp2t[(size_t)t * NBP + bp0] = make_float2(e0, e1);  // coalesced
  }
}

// ---------------- Kernel 1.4: pq table (Myers Eq bitvectors per token) ---------
__global__ __launch_bounds__(128) void k_pq(
    const int* __restrict__ labels, const int* __restrict__ llen,
    uint4* __restrict__ pqg) {
  const int b = blockIdx.x;
  const int c = threadIdx.x;
  const int m = llen[b];  // ref_len in [80,100]
  const int* __restrict__ lab = labels + b * 100;  // L == 100
  uint32_t a0 = 0, a1 = 0, a2 = 0, a3 = 0;
  const int e0 = m < 32 ? m : 32, e1 = m < 64 ? m : 64;
  const int e2 = m < 96 ? m : 96, e3 = m;
  for (int i = 0; i < e0; i++)  a0 |= (uint32_t)(lab[i] == c) << i;
  for (int i = 32; i < e1; i++) a1 |= (uint32_t)(lab[i] == c) << (i - 32);
  for (int i = 64; i < e2; i++) a2 |= (uint32_t)(lab[i] == c) << (i - 64);
  for (int i = 96; i < e3; i++) a3 |= (uint32_t)(lab[i] == c) << (i - 96);
  pqg[b * NV + c] = make_uint4(a0, a1, a2, a3);
}

// ---------------- Kernel 1.5: CTC-collapse compaction of the Eq stream ---------
// One wave per path. kept = t<el && tok!=0 && tok!=tok[t-1] (raw prev!).
// Ballot + mbcnt prefix -> compacted eqc[bp][0..nkept) of clean Eq uint4s.
__global__ __launch_bounds__(64) void k_ce(
    const uint8_t* __restrict__ tok2, const uint4* __restrict__ pqg,
    const int* __restrict__ elen, uint4* __restrict__ eqc,
    int* __restrict__ nkept) {
  __shared__ uint4 pqs[NV];  // 2 KB
  const int bp = blockIdx.x;
  const int b = bp / NP;
  const int lane = threadIdx.x;
  pqs[lane] = pqg[b * NV + lane];
  pqs[lane + 64] = pqg[b * NV + lane + 64];
  __syncthreads();
  const int el = elen[b];  // uniform
  const uint8_t* __restrict__ row = tok2 + (size_t)bp * TS;
  uint4* __restrict__ orow = eqc + (size_t)bp * ES;
  int off = 0;
  for (int t0 = 0; t0 < el; t0 += 64) {
    const int t = t0 + lane;
    const bool inb = (t < el);
    const int c = inb ? row[t] : 0;                  // blank -> not kept
    const int cp = (t == 0) ? 255 : (inb ? row[t - 1] : 255);
    const bool kept = inb && (c != 0) && (c != cp);
    const u64 mask = __ballot(kept);
    const int idx = off + (int)__builtin_amdgcn_mbcnt_hi(
        (uint32_t)(mask >> 32),
        __builtin_amdgcn_mbcnt_lo((uint32_t)mask, 0u));
    if (kept) orow[idx] = pqs[c];
    off += (int)__popcll(mask);
  }
  if (lane == 0) nkept[bp] = off;
}

// ---------------- Kernel 2: Myers bit-parallel edit distance (ungated) ---------
// grid (8,2) x 64, lane = path. Compacted stream => NO kept-gating, pure-ALU
// Myers (~60 instrs/frame). Per-lane trip count via exec mask; prefetch loop
// bound is the wave-max group count. Quad-buffered 16-frame register lead.
__device__ __forceinline__ void loadg(uint4 (&B)[4], int g, const uint4* __restrict__ rowp) {
#pragma unroll
  for (int i = 0; i < 4; i++) {
    int t = g * 4 + i;
    t = t < ES ? t : ES - 1;
    B[i] = rowp[t];
  }
}

__device__ __forceinline__ void procg(const uint4 (&B)[4], int fbase, int nk,
                                      u64 hmask,
                                      u64& Pv0, u64& Pv1, u64& Mv0, u64& Mv1,
                                      int& score) {
#pragma unroll
  for (int i = 0; i < 4; i++) {
    if (fbase + i >= nk) break;  // per-lane (exec-masked), no cndmask gating
    const u64 Eq0 = (u64)B[i].x | ((u64)B[i].y << 32);
    const u64 Eq1 = (u64)B[i].z | ((u64)B[i].w << 32);
    const u64 Xv0 = Eq0 | Mv0, Xv1 = Eq1 | Mv1;
    const u64 EP0 = Eq0 & Pv0, EP1 = Eq1 & Pv1;
    const u64 sA = EP0 + Pv0;
    const u64 sB = EP1 + Pv1 + (sA < EP0 ? 1ull : 0ull);
    const u64 Xh0 = (sA ^ Pv0) | Eq0;
    const u64 Xh1 = (sB ^ Pv1) | Eq1;
    const u64 Ph0 = Mv0 | ~(Xh0 | Pv0);
    const u64 Ph1 = Mv1 | ~(Xh1 | Pv1);
    const u64 Mh0 = Pv0 & Xh0, Mh1 = Pv1 & Xh1;
    score += (int)((Ph1 & hmask) != 0) - (int)((Mh1 & hmask) != 0);
    const u64 nPh1 = (Ph1 << 1) | (Ph0 >> 63);
    const u64 nPh0 = (Ph0 << 1) | 1ull;  // dp[i][0] = i boundary
    const u64 nMh1 = (Mh1 << 1) | (Mh0 >> 63);
    const u64 nMh0 = (Mh0 << 1);
    Pv0 = nMh0 | ~(Xv0 | nPh0);
    Pv1 = nMh1 | ~(Xv1 | nPh1);
    Mv0 = nPh0 & Xv0;
    Mv1 = nPh1 & Xv1;
  }
}

__global__ __launch_bounds__(64) void k_dp(
    const uint4* __restrict__ eqc, const int* __restrict__ nkept,
    const int* __restrict__ llen, float* __restrict__ wer) {
  const int b = blockIdx.x, h = blockIdx.y;
  const int tid = threadIdx.x;
  const bool active = (tid < 50);
  const int bp = b * NP + h * 50 + (active ? tid : 49);
  const int m = llen[b];     // ref_len in [80,100] => bit m-1 is in the high word
  const int nk = nkept[bp];  // per-lane hyp length (collapsed)
  const uint4* __restrict__ rowp = eqc + (size_t)bp * ES;
  u64 Pv0 = ~0ull, Pv1 = ~0ull, Mv0 = 0ull, Mv1 = 0ull;
  int score = m;
  const u64 hmask = 1ull << ((m - 1) & 63);

  const int ngl = (nk + 3) >> 2;
  int ngmax = ngl;           // wave-max group count (uniform prefetch bound)
  for (int off = 1; off < 64; off <<= 1) {
    const int o = __shfl_xor(ngmax, off);
    ngmax = o > ngmax ? o : ngmax;
  }
  uint4 B0[4], B1[4], B2[4], B3[4];
  loadg(B0, 0, rowp); loadg(B1, 1, rowp);
  loadg(B2, 2, rowp); loadg(B3, 3, rowp);
  int g = 0;
  while (g + 4 <= ngmax) {
    procg(B0, (g    ) * 4, nk, hmask, Pv0, Pv1, Mv0, Mv1, score);
    loadg(B0, g + 4, rowp);
    procg(B1, (g + 1) * 4, nk, hmask, Pv0, Pv1, Mv0, Mv1, score);
    loadg(B1, g + 5, rowp);
    procg(B2, (g + 2) * 4, nk, hmask, Pv0, Pv1, Mv0, Mv1, score);
    loadg(B2, g + 6, rowp);
    procg(B3, (g + 3) * 4, nk, hmask, Pv0, Pv1, Mv0, Mv1, score);
    loadg(B3, g + 7, rowp);
    g += 4;
  }
  if (g     < ngmax) procg(B0, (g    ) * 4, nk, hmask, Pv0, Pv1, Mv0, Mv1, score);
  if (g + 1 < ngmax) procg(B1, (g + 1) * 4, nk, hmask, Pv0, Pv1, Mv0, Mv1, score);
  if (g + 2 < ngmax) procg(B2, (g + 2) * 4, nk, hmask, Pv0, Pv1, Mv0, Mv1, score);
  if (active) wer[bp] = (float)score;
}

// ---------------- Kernel 3: per-path logp partial sums (4 t-chunks) ------------
__global__ __launch_bounds__(128) void k_red(
    const float* __restrict__ lp2t, const int* __restrict__ elen,
    double* __restrict__ pred) {
  const int b = blockIdx.x, k = blockIdx.y;
  const int tid = threadIdx.x;
  const bool active = (tid < NP);
  const int p = active ? tid : NP - 1;
  const int el = elen[b];  // uniform
  const int t0 = k * 125;
  const int t1 = (t0 + 125 < el) ? t0 + 125 : el;
  const float* __restrict__ col = lp2t + b * NP + p;
  double s = 0.0;
#pragma unroll 8
  for (int t = t0; t < t1; t++) s += (double)col[(size_t)t * NBP];
  if (active) pred[(size_t)(b * NP + p) * 4 + k] = s;
}

// ---------------- Kernel 4: per-b softmax + expected WER + mean ----------------
__global__ __launch_bounds__(512) void k_fin(
    const double* __restrict__ pred, const float* __restrict__ wer,
    float* __restrict__ out) {
  __shared__ float partial[NB];
  const int w = threadIdx.x >> 6, lane = threadIdx.x & 63;  // w = b
  const int base = w * NP;
  float l0 = -1e30f, l1 = -1e30f;
  if (lane < NP) {
    const double* pr = pred + (size_t)(base + lane) * 4;
    l0 = (float)(pr[0] + pr[1] + pr[2] + pr[3]);
  }
  if (lane + 64 < NP) {
    const double* pr = pred + (size_t)(base + lane + 64) * 4;
    l1 = (float)(pr[0] + pr[1] + pr[2] + pr[3]);
  }
  float mx = fmaxf(l0, l1);
  for (int off = 1; off < 64; off <<= 1) mx = fmaxf(mx, __shfl_xor(mx, off));
  const float e0 = (lane < NP) ? __expf(l0 - mx) : 0.0f;
  const float e1 = (lane + 64 < NP) ? __expf(l1 - mx) : 0.0f;
  const float w0 = (lane < NP) ? wer[base + lane] : 0.0f;
  const float w1 = (lane + 64 < NP) ? wer[base + lane + 64] : 0.0f;
  float s = e0 + e1;
  float a = e0 * w0 + e1 * w1;
  for (int off = 1; off < 64; off <<= 1) {
    s += __shfl_xor(s, off);
    a += __shfl_xor(a, off);
  }
  if (lane == 0) partial[w] = a / s;
  __syncthreads();
  if (threadIdx.x == 0) {
    float tot = 0.0f;
    for (int i = 0; i < NB; i++) tot += partial[i];
    out[0] = tot * (1.0f / (float)NBP);
  }
}

extern "C" void kernel_launch(void* const* d_in, const int* in_sizes, int n_in,
                              void* d_out, int out_size, void* d_ws, size_t ws_size,
                              hipStream_t stream) {
  const float* em     = (const float*)d_in[0];
  const int*   elen   = (const int*)d_in[1];
  const int*   labels = (const int*)d_in[2];
  const int*   llen   = (const int*)d_in[3];
  float* out = (float*)d_out;
  char* ws = (char*)d_ws;
  uint4*   eqc   = (uint4*)ws;                        // 800*500*16 = 6,400,000
  uint8_t* tok2  = (uint8_t*)(ws + 6400000);          // 409,600
  float*   lp2t  = (float*)(ws + 6809600);            // 1,600,000 ([t][bp])
  float*   wer   = (float*)(ws + 8409600);            // 3,200
  double*  pred  = (double*)(ws + 8412800);           // 25,600
  int*     nkept = (int*)(ws + 8438400);              // 3,200
  uint4*   pqg   = (uint4*)(ws + 8441600);            // 16,384

  k_sample<<<dim3(1563), dim3(256), 0, stream>>>(em, elen, tok2, lp2t, 0);
  k_sample<<<dim3(1562), dim3(256), 0, stream>>>(em, elen, tok2, lp2t, 1563 * 64);
  k_pq<<<dim3(NB), dim3(128), 0, stream>>>(labels, llen, pqg);
  k_ce<<<dim3(NBP), dim3(64), 0, stream>>>(tok2, pqg, elen, eqc, nkept);
  k_dp<<<dim3(NB, 2), dim3(64), 0, stream>>>(eqc, nkept, llen, wer);
  k_red<<<dim3(NB, 4), dim3(128), 0, stream>>>(lp2t, elen, pred);
  k_fin<<<dim3(1), dim3(512), 0, stream>>>(pred, wer, out);
}